// Round 1
// baseline (77258.472 us; speedup 1.0000x reference)
//
#include <hip/hip_runtime.h>
#include <hip/hip_cooperative_groups.h>
#include <cmath>

namespace cg = cooperative_groups;

static constexpr int NB = 64;    // batch
static constexpr int NT = 256;   // time steps
static constexpr int NE = 1024;  // input embedding
static constexpr int NH = 1024;  // hidden
static constexpr int NL = 3;     // layers
static constexpr int NG = 4 * NH;            // 4096 gate rows
static constexpr int STATE = NL * NB * NH;   // 196608 elements
static constexpr int NTHREADS = 256 * 256;   // grid threads

__device__ __forceinline__ float sigmoidf_(float x) {
    return 1.0f / (1.0f + __expf(-x));
}

#define FMA4(acc, xv, wv)                                    \
    acc = fmaf((xv).x, (wv).x, acc);                         \
    acc = fmaf((xv).y, (wv).y, acc);                         \
    acc = fmaf((xv).z, (wv).z, acc);                         \
    acc = fmaf((xv).w, (wv).w, acc);

// grid: 256 blocks x 256 threads, one thread per output unit (b, n).
// Within a wave: b = lane (0..63), n uniform -> weight loads are scalar.
__global__ void __launch_bounds__(256, 1)
lstm_kernel(const float* __restrict__ inputs,   // (B,T,E)
            const float* __restrict__ enc,      // (1,B,H)
            const float* __restrict__ W_ih,     // (L,4H,E)
            const float* __restrict__ W_hh,     // (L,4H,H)
            const float* __restrict__ bias,     // (L,4H)
            float* __restrict__ out,            // hT | cT | outs
            float* __restrict__ ws)
{
    cg::grid_group grid = cg::this_grid();
    const int tid = threadIdx.x;
    const int b   = tid & 63;
    const int wv  = __builtin_amdgcn_readfirstlane(tid >> 6);
    const int n   = blockIdx.x * 4 + wv;            // 0..1023
    const int g   = blockIdx.x * 256 + tid;         // 0..65535

    float* hT    = out;                 // (L,B,H) -> doubles as h buffer 0
    float* cT    = out + STATE;         // (L,B,H) -> in-place cell state
    float* outs  = out + 2 * STATE;     // (B,T,H)
    float* hbuf0 = hT;
    float* hbuf1 = ws;                  // needs STATE*4 = 768 KiB of ws
    float* cbuf  = cT;

    // init: h0 = tile(encoder_finals, L), c0 = 0
    for (int i = g; i < STATE; i += NTHREADS) {
        hbuf0[i] = enc[i % (NB * NH)];
        cbuf[i]  = 0.0f;
    }
    grid.sync();

    for (int t = 0; t < NT; ++t) {
        float* hprev = (t & 1) ? hbuf1 : hbuf0;
        float* hcur  = (t & 1) ? hbuf0 : hbuf1;   // t=255 writes hbuf0 == hT
        for (int l = 0; l < NL; ++l) {
            const float* xrow = (l == 0)
                ? inputs + ((size_t)b * NT + t) * NE
                : hcur + ((size_t)(l - 1) * NB + b) * NH;
            const float* hrow = hprev + ((size_t)l * NB + b) * NH;
            const float* wih  = W_ih + (size_t)l * NG * NE + (size_t)n * NE;
            const float* whh  = W_hh + (size_t)l * NG * NH + (size_t)n * NH;
            const float* bl   = bias + (size_t)l * NG;

            float ai = bl[n];
            float af = bl[NH + n];
            float ag = bl[2 * NH + n];
            float ao = bl[3 * NH + n];

            // x (or lower-layer h) @ W_ih^T : K = NE
            {
                const float* w0 = wih;
                const float* w1 = wih + (size_t)1 * NH * NE;
                const float* w2 = wih + (size_t)2 * NH * NE;
                const float* w3 = wih + (size_t)3 * NH * NE;
                #pragma unroll 4
                for (int k = 0; k < NE; k += 4) {
                    const float4 xv = *reinterpret_cast<const float4*>(xrow + k);
                    const float4 a0 = *reinterpret_cast<const float4*>(w0 + k);
                    const float4 a1 = *reinterpret_cast<const float4*>(w1 + k);
                    const float4 a2 = *reinterpret_cast<const float4*>(w2 + k);
                    const float4 a3 = *reinterpret_cast<const float4*>(w3 + k);
                    FMA4(ai, xv, a0);
                    FMA4(af, xv, a1);
                    FMA4(ag, xv, a2);
                    FMA4(ao, xv, a3);
                }
            }
            // h @ W_hh^T : K = NH
            {
                const float* w0 = whh;
                const float* w1 = whh + (size_t)1 * NH * NH;
                const float* w2 = whh + (size_t)2 * NH * NH;
                const float* w3 = whh + (size_t)3 * NH * NH;
                #pragma unroll 4
                for (int k = 0; k < NH; k += 4) {
                    const float4 hv = *reinterpret_cast<const float4*>(hrow + k);
                    const float4 a0 = *reinterpret_cast<const float4*>(w0 + k);
                    const float4 a1 = *reinterpret_cast<const float4*>(w1 + k);
                    const float4 a2 = *reinterpret_cast<const float4*>(w2 + k);
                    const float4 a3 = *reinterpret_cast<const float4*>(w3 + k);
                    FMA4(ai, hv, a0);
                    FMA4(af, hv, a1);
                    FMA4(ag, hv, a2);
                    FMA4(ao, hv, a3);
                }
            }

            // LSTM cell (PyTorch gate order i, f, g, o)
            const float iv = sigmoidf_(ai);
            const float fv = sigmoidf_(af);
            const float gv = tanhf(ag);
            const float ov = sigmoidf_(ao);
            const size_t idx = ((size_t)l * NB + b) * NH + n;
            const float cnew = fv * cbuf[idx] + iv * gv;
            const float hnew = ov * tanhf(cnew);
            cbuf[idx] = cnew;
            hcur[idx] = hnew;
            if (l == NL - 1) {
                outs[((size_t)b * NT + t) * NH + n] = hnew;
            }
            grid.sync();
        }
    }
    // final h state: t=255 (odd) wrote hbuf0 == out's hT region; c is in place.
}

extern "C" void kernel_launch(void* const* d_in, const int* in_sizes, int n_in,
                              void* d_out, int out_size, void* d_ws, size_t ws_size,
                              hipStream_t stream) {
    const float* inputs = (const float*)d_in[0];
    const float* enc    = (const float*)d_in[1];
    const float* W_ih   = (const float*)d_in[2];
    const float* W_hh   = (const float*)d_in[3];
    const float* bias   = (const float*)d_in[4];
    float* out = (float*)d_out;
    float* ws  = (float*)d_ws;

    void* args[] = { &inputs, &enc, &W_ih, &W_hh, &bias, &out, &ws };
    hipLaunchCooperativeKernel((const void*)lstm_kernel,
                               dim3(256), dim3(256), args, 0, stream);
}